// Round 1
// baseline (24847.520 us; speedup 1.0000x reference)
//
#include <hip/hip_runtime.h>
#include <hip/hip_bf16.h>
#include <math.h>

// Problem constants (GPT-2 small, B=2, S=1024)
#define VOCAB 50257
#define DMODEL 768
#define NHEAD 12
#define NPOS 1024
#define NLAYER 12
#define BATCH 2
#define SEQ 1024
#define HEADD 64
#define DFF 3072
#define MROWS (BATCH * SEQ)   // 2048

// ---------------------------------------------------------------------------
// pos_ids: cumsum(mask)-1, pinned to 0 where mask==0
// ---------------------------------------------------------------------------
__global__ void pos_ids_kernel(const float* __restrict__ mask, int* __restrict__ pos_ids) {
    int tid = blockIdx.x * blockDim.x + threadIdx.x;
    if (tid >= BATCH * SEQ) return;
    int b = tid / SEQ;
    int s = tid % SEQ;
    float am = mask[tid];
    if (am == 0.0f) { pos_ids[tid] = 0; return; }
    float acc = 0.0f;
    const float* row = mask + b * SEQ;
    for (int t = 0; t <= s; ++t) acc += row[t];
    pos_ids[tid] = (int)(acc - 1.0f);
}

// ---------------------------------------------------------------------------
// embedding: x[bs, d] = tok_emb[ids[bs]][d] + pos_emb[pos_ids[bs]][d]
// ---------------------------------------------------------------------------
__global__ void embed_kernel(const int* __restrict__ ids, const int* __restrict__ pos_ids,
                             const float* __restrict__ tok_emb, const float* __restrict__ pos_emb,
                             float* __restrict__ x) {
    int idx = blockIdx.x * blockDim.x + threadIdx.x;
    if (idx >= MROWS * DMODEL) return;
    int bs = idx / DMODEL;
    int d  = idx % DMODEL;
    int id = ids[bs];
    int p  = pos_ids[bs];
    x[idx] = tok_emb[(size_t)id * DMODEL + d] + pos_emb[(size_t)p * DMODEL + d];
}

// ---------------------------------------------------------------------------
// LayerNorm: one block (256 threads) per row of 768
// ---------------------------------------------------------------------------
__device__ inline float wave_sum64(float v) {
    #pragma unroll
    for (int off = 32; off >= 1; off >>= 1) v += __shfl_xor(v, off, 64);
    return v;
}

__global__ __launch_bounds__(256) void layernorm_kernel(
    const float* __restrict__ x, const float* __restrict__ g, const float* __restrict__ b,
    float* __restrict__ out) {
    int row = blockIdx.x;
    int tid = threadIdx.x;
    const float* xr = x + (size_t)row * DMODEL;
    float v0 = xr[tid], v1 = xr[tid + 256], v2 = xr[tid + 512];

    __shared__ float red[4];
    int wave = tid >> 6, lane = tid & 63;

    float s = wave_sum64(v0 + v1 + v2);
    if (lane == 0) red[wave] = s;
    __syncthreads();
    float mean = (red[0] + red[1] + red[2] + red[3]) * (1.0f / DMODEL);
    __syncthreads();

    float d0 = v0 - mean, d1 = v1 - mean, d2 = v2 - mean;
    float s2 = wave_sum64(d0 * d0 + d1 * d1 + d2 * d2);
    if (lane == 0) red[wave] = s2;
    __syncthreads();
    float var = (red[0] + red[1] + red[2] + red[3]) * (1.0f / DMODEL);
    float inv = 1.0f / sqrtf(var + 1e-5f);

    float* outr = out + (size_t)row * DMODEL;
    outr[tid]       = d0 * inv * g[tid]       + b[tid];
    outr[tid + 256] = d1 * inv * g[tid + 256] + b[tid + 256];
    outr[tid + 512] = d2 * inv * g[tid + 512] + b[tid + 512];
}

// ---------------------------------------------------------------------------
// GEMM: C[M,N] = A[M,K] @ B  (+bias)(+GELU)(+Res)
//   TRANSB=0: B is (K,N) row-major.  TRANSB=1: B is (N,K) row-major.
// 64x64 tile, BK=16, 256 threads, 4x4 microtile. M%64==0, K%16==0 assumed.
// ---------------------------------------------------------------------------
#define BM 64
#define BN 64
#define BKT 16

template<int TRANSB, int GELU>
__global__ __launch_bounds__(256) void gemm_kernel(
    const float* __restrict__ A, const float* __restrict__ B,
    const float* __restrict__ bias, const float* __restrict__ Res,
    float* __restrict__ C, int M, int N, int K) {
    __shared__ __align__(16) float As[BKT][BM];
    __shared__ __align__(16) float Bs[BKT][BN];

    int tid = threadIdx.x;
    int tx = tid & 15, ty = tid >> 4;
    int m0 = blockIdx.y * BM, n0 = blockIdx.x * BN;

    float acc[4][4] = {};

    // A-tile load mapping: 64 rows x 16 k, float4 per thread
    int arow = tid >> 2;           // 0..63
    int akq  = (tid & 3) << 2;     // 0,4,8,12
    // B-tile (nn): 16 k-rows x 64 cols
    int bkrow = tid >> 4;          // 0..15
    int bcol  = (tid & 15) << 2;   // 0..60
    // B-tile (nt): 64 n-rows x 16 k
    int bn  = tid >> 2;            // 0..63
    int bkq = (tid & 3) << 2;

    for (int k0 = 0; k0 < K; k0 += BKT) {
        float4 av = *(const float4*)(A + (size_t)(m0 + arow) * K + k0 + akq);
        As[akq + 0][arow] = av.x; As[akq + 1][arow] = av.y;
        As[akq + 2][arow] = av.z; As[akq + 3][arow] = av.w;

        if (TRANSB) {
            float4 bv = make_float4(0.f, 0.f, 0.f, 0.f);
            if (n0 + bn < N)
                bv = *(const float4*)(B + (size_t)(n0 + bn) * K + k0 + bkq);
            Bs[bkq + 0][bn] = bv.x; Bs[bkq + 1][bn] = bv.y;
            Bs[bkq + 2][bn] = bv.z; Bs[bkq + 3][bn] = bv.w;
        } else {
            if (n0 + bcol + 3 < N) {
                *(float4*)&Bs[bkrow][bcol] =
                    *(const float4*)(B + (size_t)(k0 + bkrow) * N + n0 + bcol);
            } else {
                #pragma unroll
                for (int j = 0; j < 4; ++j)
                    Bs[bkrow][bcol + j] =
                        (n0 + bcol + j < N) ? B[(size_t)(k0 + bkrow) * N + n0 + bcol + j] : 0.f;
            }
        }
        __syncthreads();

        #pragma unroll
        for (int kk = 0; kk < BKT; ++kk) {
            float4 a4 = *(const float4*)&As[kk][ty << 2];
            float4 b4 = *(const float4*)&Bs[kk][tx << 2];
            float avr[4] = {a4.x, a4.y, a4.z, a4.w};
            float bvr[4] = {b4.x, b4.y, b4.z, b4.w};
            #pragma unroll
            for (int i = 0; i < 4; ++i)
                #pragma unroll
                for (int j = 0; j < 4; ++j)
                    acc[i][j] += avr[i] * bvr[j];
        }
        __syncthreads();
    }

    #pragma unroll
    for (int i = 0; i < 4; ++i) {
        int m = m0 + (ty << 2) + i;
        #pragma unroll
        for (int j = 0; j < 4; ++j) {
            int n = n0 + (tx << 2) + j;
            if (n < N) {
                float v = acc[i][j];
                if (bias) v += bias[n];
                if (GELU) v = v * 0.5f * (1.0f + erff(v * 0.70710678118654752f));
                if (Res)  v += Res[(size_t)m * N + n];
                C[(size_t)m * N + n] = v;
            }
        }
    }
}

// ---------------------------------------------------------------------------
// Flash attention: one wave per (b, h, q). lane = head dim (HD==64).
// q,k,v in (B*S, D) layout with head h at columns [h*64, h*64+64).
// ---------------------------------------------------------------------------
__global__ __launch_bounds__(256) void attention_kernel(
    const float* __restrict__ q, const float* __restrict__ k, const float* __restrict__ v,
    const float* __restrict__ mask, float* __restrict__ out) {
    int wid  = blockIdx.x * 4 + (threadIdx.x >> 6);
    int lane = threadIdx.x & 63;
    int qi = wid % SEQ;
    int h  = (wid / SEQ) % NHEAD;
    int b  = wid / (SEQ * NHEAD);

    size_t qoff  = (size_t)(b * SEQ + qi) * DMODEL + h * HEADD + lane;
    size_t kbase = (size_t)b * SEQ * DMODEL + h * HEADD + lane;

    float qv = q[qoff] * 0.125f;   // 1/sqrt(64)

    float m = -INFINITY, l = 0.0f, o = 0.0f;
    const float* mrow = mask + b * SEQ;

    for (int j = 0; j <= qi; ++j) {
        float kv = k[kbase + (size_t)j * DMODEL];
        float s = qv * kv;
        #pragma unroll
        for (int off = 32; off >= 1; off >>= 1) s += __shfl_xor(s, off, 64);
        if (mrow[j] == 0.0f) s = -3.402823466e38f;  // finfo(f32).min
        float m_new = fmaxf(m, s);
        float alpha = expf(m - m_new);
        float p = expf(s - m_new);
        l = l * alpha + p;
        o = o * alpha + p * v[kbase + (size_t)j * DMODEL];
        m = m_new;
    }
    out[qoff] = o / l;
}

// ---------------------------------------------------------------------------
// Host launcher
// ---------------------------------------------------------------------------
static inline size_t align_up(size_t x, size_t a) { return (x + a - 1) & ~(a - 1); }

extern "C" void kernel_launch(void* const* d_in, const int* in_sizes, int n_in,
                              void* d_out, int out_size, void* d_ws, size_t ws_size,
                              hipStream_t stream) {
    const int*   input_ids = (const int*)d_in[0];
    const float* amask     = (const float*)d_in[1];
    const float* tok_emb   = (const float*)d_in[2];
    const float* pos_emb   = (const float*)d_in[3];
    const float* ln1_g = (const float*)d_in[4];
    const float* ln1_b = (const float*)d_in[5];
    const float* Wq = (const float*)d_in[6];
    const float* bq = (const float*)d_in[7];
    const float* Wk = (const float*)d_in[8];
    const float* bk = (const float*)d_in[9];
    const float* Wv = (const float*)d_in[10];
    const float* bv = (const float*)d_in[11];
    const float* Wp = (const float*)d_in[12];
    const float* bp = (const float*)d_in[13];
    const float* ln2_g = (const float*)d_in[14];
    const float* ln2_b = (const float*)d_in[15];
    const float* W1 = (const float*)d_in[16];
    const float* b1 = (const float*)d_in[17];
    const float* W2 = (const float*)d_in[18];
    const float* b2 = (const float*)d_in[19];
    const float* lnf_g = (const float*)d_in[20];
    const float* lnf_b = (const float*)d_in[21];

    float* logits = (float*)d_out;

    // Workspace carve-out
    char* ws = (char*)d_ws;
    size_t off = 0;
    auto carve = [&](size_t nbytes) -> char* {
        char* p = ws + off;
        off = align_up(off + nbytes, 256);
        return p;
    };
    int*   pos_ids = (int*)  carve((size_t)MROWS * sizeof(int));
    float* x    = (float*)carve((size_t)MROWS * DMODEL * sizeof(float));
    float* h    = (float*)carve((size_t)MROWS * DMODEL * sizeof(float));
    float* qb   = (float*)carve((size_t)MROWS * DMODEL * sizeof(float));
    float* kb   = (float*)carve((size_t)MROWS * DMODEL * sizeof(float));
    float* vb   = (float*)carve((size_t)MROWS * DMODEL * sizeof(float));
    float* attn = (float*)carve((size_t)MROWS * DMODEL * sizeof(float));
    float* ff   = (float*)carve((size_t)MROWS * DFF    * sizeof(float));
    (void)ws_size; (void)in_sizes; (void)n_in; (void)out_size;

    // 1. position ids + embedding
    pos_ids_kernel<<<(MROWS + 255) / 256, 256, 0, stream>>>(amask, pos_ids);
    embed_kernel<<<(MROWS * DMODEL + 255) / 256, 256, 0, stream>>>(
        input_ids, pos_ids, tok_emb, pos_emb, x);

    dim3 gD((DMODEL + BN - 1) / BN, (MROWS + BM - 1) / BM);     // 12 x 32
    dim3 gF((DFF    + BN - 1) / BN, (MROWS + BM - 1) / BM);     // 48 x 32
    dim3 gV((VOCAB  + BN - 1) / BN, (MROWS + BM - 1) / BM);     // 786 x 32

    for (int l = 0; l < NLAYER; ++l) {
        const size_t oD  = (size_t)l * DMODEL;
        const size_t oDD = (size_t)l * DMODEL * DMODEL;
        const size_t oDF = (size_t)l * DMODEL * DFF;

        // h = LN1(x)
        layernorm_kernel<<<MROWS, 256, 0, stream>>>(x, ln1_g + oD, ln1_b + oD, h);
        // q,k,v = h @ W + b
        gemm_kernel<0, 0><<<gD, 256, 0, stream>>>(h, Wq + oDD, bq + oD, nullptr, qb,
                                                  MROWS, DMODEL, DMODEL);
        gemm_kernel<0, 0><<<gD, 256, 0, stream>>>(h, Wk + oDD, bk + oD, nullptr, kb,
                                                  MROWS, DMODEL, DMODEL);
        gemm_kernel<0, 0><<<gD, 256, 0, stream>>>(h, Wv + oDD, bv + oD, nullptr, vb,
                                                  MROWS, DMODEL, DMODEL);
        // attn = softmax(qk^T * scale + mask) @ v
        attention_kernel<<<BATCH * NHEAD * SEQ / 4, 256, 0, stream>>>(qb, kb, vb, amask, attn);
        // x = x + attn @ Wp + bp
        gemm_kernel<0, 0><<<gD, 256, 0, stream>>>(attn, Wp + oDD, bp + oD, x, x,
                                                  MROWS, DMODEL, DMODEL);
        // h = LN2(x)
        layernorm_kernel<<<MROWS, 256, 0, stream>>>(x, ln2_g + oD, ln2_b + oD, h);
        // ff = gelu(h @ W1 + b1)
        gemm_kernel<0, 1><<<gF, 256, 0, stream>>>(h, W1 + oDF, b1 + (size_t)l * DFF, nullptr, ff,
                                                  MROWS, DFF, DMODEL);
        // x = x + ff @ W2 + b2
        gemm_kernel<0, 0><<<gD, 256, 0, stream>>>(ff, W2 + oDF, b2 + oD, x, x,
                                                  MROWS, DMODEL, DFF);
    }

    // final LN + tied LM head: logits = h @ tok_emb^T
    layernorm_kernel<<<MROWS, 256, 0, stream>>>(x, lnf_g, lnf_b, h);
    gemm_kernel<1, 0><<<gV, 256, 0, stream>>>(h, tok_emb, nullptr, nullptr, logits,
                                              MROWS, VOCAB, DMODEL);
}